// Round 12
// baseline (189.825 us; speedup 1.0000x reference)
//
#include <hip/hip_runtime.h>
#include <math.h>

#define NEGM (-1e30f)

__device__ __forceinline__ float4 ld4(const float* p) { return *(const float4*)p; }
__device__ __forceinline__ void fma4(float4& a, float s, const float4 w) {
    a.x += s * w.x; a.y += s * w.y; a.z += s * w.z; a.w += s * w.w;
}
__device__ __forceinline__ float dot4(const float4 a, const float4 b) {
    return (a.x * b.x + a.y * b.y) + (a.z * b.z + a.w * b.w);
}
__device__ __forceinline__ void upd4(float4& p, float rm, float rw, const float4 a) {
    p.x = p.x * rm + rw * a.x; p.y = p.y * rm + rw * a.y;
    p.z = p.z * rm + rw * a.z; p.w = p.w * rm + rw * a.w;
}
__device__ __forceinline__ void relu4(float4& a) {
    a.x = fmaxf(a.x, 0.f); a.y = fmaxf(a.y, 0.f);
    a.z = fmaxf(a.z, 0.f); a.w = fmaxf(a.w, 0.f);
}

// ---------------- Kernel A: kick encoder + inner pool ----------------
// One THREAD per (row, game): serial in-lane online softmax, zero shuffles,
// zero barriers after weight staging. 2-kick unroll shares W_ke LDS reads.
__global__ __launch_bounds__(256) void pool_kernel(
    const float* __restrict__ x_kicks,
    const float* __restrict__ W_ke, const float* __restrict__ b_ke,
    const float* __restrict__ q_inner,
    const int* __restrict__ inner_mask,
    float* __restrict__ pg_out)
{
    __shared__ float s_wke[256];
    const int tid = threadIdx.x;
    s_wke[tid] = W_ke[tid];
    __syncthreads();

    const int t = blockIdx.x * 256 + tid;        // 0 .. 278527
    const int row = t / 17;
    const int game = t - row * 17;
    const float* xb = x_kicks + ((size_t)row * 204 + game * 12) * 16;
    const int* mp = inner_mask + (size_t)row * 204 + game * 12;

    const int4 mka = *(const int4*)(mp);
    const int4 mkb = *(const int4*)(mp + 4);
    const int4 mkc = *(const int4*)(mp + 8);
    const int mks[12] = {mka.x, mka.y, mka.z, mka.w,
                         mkb.x, mkb.y, mkb.z, mkb.w,
                         mkc.x, mkc.y, mkc.z, mkc.w};

    const float4 qi0 = ld4(q_inner + 0), qi1 = ld4(q_inner + 4);
    const float4 qi2 = ld4(q_inner + 8), qi3 = ld4(q_inner + 12);
    const float4 bk0 = ld4(b_ke + 0), bk1 = ld4(b_ke + 4);
    const float4 bk2 = ld4(b_ke + 8), bk3 = ld4(b_ke + 12);

    float m = NEGM, s = 0.f;
    float4 p0 = {0,0,0,0}, p1 = p0, p2 = p0, p3 = p0;

    #pragma unroll
    for (int h = 0; h < 6; ++h) {
        // load 2 kicks (128 B contiguous per thread)
        float xa[16], xc[16];
        {
            const float* pa = xb + (2 * h) * 16;
            float4 t0 = ld4(pa + 0), t1 = ld4(pa + 4), t2 = ld4(pa + 8), t3 = ld4(pa + 12);
            xa[0]=t0.x; xa[1]=t0.y; xa[2]=t0.z; xa[3]=t0.w;
            xa[4]=t1.x; xa[5]=t1.y; xa[6]=t1.z; xa[7]=t1.w;
            xa[8]=t2.x; xa[9]=t2.y; xa[10]=t2.z; xa[11]=t2.w;
            xa[12]=t3.x; xa[13]=t3.y; xa[14]=t3.z; xa[15]=t3.w;
            float4 u0 = ld4(pa + 16), u1 = ld4(pa + 20), u2 = ld4(pa + 24), u3 = ld4(pa + 28);
            xc[0]=u0.x; xc[1]=u0.y; xc[2]=u0.z; xc[3]=u0.w;
            xc[4]=u1.x; xc[5]=u1.y; xc[6]=u1.z; xc[7]=u1.w;
            xc[8]=u2.x; xc[9]=u2.y; xc[10]=u2.z; xc[11]=u2.w;
            xc[12]=u3.x; xc[13]=u3.y; xc[14]=u3.z; xc[15]=u3.w;
        }
        float4 A0 = bk0, A1 = bk1, A2 = bk2, A3 = bk3;
        float4 C0 = bk0, C1 = bk1, C2 = bk2, C3 = bk3;
        #pragma unroll
        for (int i = 0; i < 16; ++i) {
            float4 w0 = *(float4*)&s_wke[i * 16 + 0];
            float4 w1 = *(float4*)&s_wke[i * 16 + 4];
            float4 w2 = *(float4*)&s_wke[i * 16 + 8];
            float4 w3 = *(float4*)&s_wke[i * 16 + 12];
            float va = xa[i], vc = xc[i];
            fma4(A0, va, w0); fma4(A1, va, w1); fma4(A2, va, w2); fma4(A3, va, w3);
            fma4(C0, vc, w0); fma4(C1, vc, w1); fma4(C2, vc, w2); fma4(C3, vc, w3);
        }
        relu4(A0); relu4(A1); relu4(A2); relu4(A3);
        relu4(C0); relu4(C1); relu4(C2); relu4(C3);

        float scA = (dot4(A0,qi0) + dot4(A1,qi1) + dot4(A2,qi2) + dot4(A3,qi3)) * 0.25f;
        float scC = (dot4(C0,qi0) + dot4(C1,qi1) + dot4(C2,qi2) + dot4(C3,qi3)) * 0.25f;
        const int mkA = mks[2 * h], mkC = mks[2 * h + 1];

        {   // online update: kick A
            float scm = mkA ? scA : NEGM;
            float mn = fmaxf(m, scm);
            float rm = __expf(m - mn);
            float rw = mkA ? __expf(scA - mn) : 0.f;
            s = s * rm + rw;
            upd4(p0, rm, rw, A0); upd4(p1, rm, rw, A1);
            upd4(p2, rm, rw, A2); upd4(p3, rm, rw, A3);
            m = mn;
        }
        {   // online update: kick C
            float scm = mkC ? scC : NEGM;
            float mn = fmaxf(m, scm);
            float rm = __expf(m - mn);
            float rw = mkC ? __expf(scC - mn) : 0.f;
            s = s * rm + rw;
            upd4(p0, rm, rw, C0); upd4(p1, rm, rw, C1);
            upd4(p2, rm, rw, C2); upd4(p3, rm, rw, C3);
            m = mn;
        }
    }

    const float inv = 1.f / s;                   // kick 0 always valid -> s > 0
    float* op = pg_out + (size_t)row * 272 + game * 16;
    p0.x*=inv; p0.y*=inv; p0.z*=inv; p0.w*=inv;
    p1.x*=inv; p1.y*=inv; p1.z*=inv; p1.w*=inv;
    p2.x*=inv; p2.y*=inv; p2.z*=inv; p2.w*=inv;
    p3.x*=inv; p3.y*=inv; p3.z*=inv; p3.w*=inv;
    *(float4*)(op + 0)  = p0;
    *(float4*)(op + 4)  = p1;
    *(float4*)(op + 8)  = p2;
    *(float4*)(op + 12) = p3;
}

// ---------------- Kernel B: phases B-E (game encoder .. LayerNorm) ----------------
// One wave per row, 2 rows per block (R10 measured-best structure).
__global__ __launch_bounds__(128) void hist_kernel(
    const float* __restrict__ pg_in,
    const float* __restrict__ W_ge, const float* __restrict__ b_ge,
    const float* __restrict__ pos_emb, const float* __restrict__ q_outer,
    const float* __restrict__ log_temp,
    const float* __restrict__ ln_g, const float* __restrict__ ln_b,
    const int* __restrict__ outer_mask,
    float* __restrict__ hist)
{
    __shared__ float s_wge[512];        // W_ge [16][32]
    __shared__ float s_qout[256];       // q_outer [8][32]
    __shared__ float s_pg[2][17 * 20];  // per_game, stride 20
    __shared__ float s_enc[2][17 * 36]; // encoded, stride 36
    __shared__ float s_ao[2][136];      // outer scores -> weights

    const int tid  = threadIdx.x;       // 0..127
    const int wid  = tid >> 6;          // 0..1
    const int lane = tid & 63;
    const int b    = blockIdx.x * 2 + wid;

    s_qout[tid] = q_outer[tid];
    s_qout[tid + 128] = q_outer[tid + 128];
    s_wge[tid] = W_ge[tid];
    s_wge[tid + 128] = W_ge[tid + 128];
    s_wge[tid + 256] = W_ge[tid + 256];
    s_wge[tid + 384] = W_ge[tid + 384];

    // stage this row's per_game (272 floats, coalesced)
    {
        const float* pgb = pg_in + (size_t)b * 272;
        float4 v = ld4(pgb + lane * 4);
        const int g = lane >> 2, d = (lane & 3) * 4;
        *(float4*)&s_pg[wid][g * 20 + d] = v;
        if (lane < 4) {
            float4 v2 = ld4(pgb + 256 + lane * 4);
            *(float4*)&s_pg[wid][16 * 20 + lane * 4] = v2;
        }
    }
    __syncthreads();

    float* pg  = s_pg[wid];
    float* enc = s_enc[wid];
    float* ao  = s_ao[wid];

    // ---------- Phase B: game encoder + pos emb -> enc[17][32] ----------
    for (int t = lane; t < 136; t += 64) {
        const int g = t >> 3, dq = t & 7;
        float4 acc = ld4(b_ge + dq * 4);
        #pragma unroll
        for (int i = 0; i < 16; ++i) {
            float pv = pg[g * 20 + i];
            fma4(acc, pv, *(float4*)&s_wge[i * 32 + dq * 4]);
        }
        float4 pe = ld4(pos_emb + g * 32 + dq * 4);
        acc.x = fmaxf(acc.x, 0.f) + pe.x; acc.y = fmaxf(acc.y, 0.f) + pe.y;
        acc.z = fmaxf(acc.z, 0.f) + pe.z; acc.w = fmaxf(acc.w, 0.f) + pe.w;
        *(float4*)&enc[g * 36 + dq * 4] = acc;
    }
    __syncthreads();

    // ---------- Phase C: outer attention scores ao[8][17] ----------
    for (int t = lane; t < 136; t += 64) {
        const int q = t / 17, g = t - q * 17;
        float4 acc = {0.f, 0.f, 0.f, 0.f};
        #pragma unroll
        for (int i4 = 0; i4 < 8; ++i4) {
            float4 ev = *(float4*)&enc[g * 36 + i4 * 4];
            float4 qv = *(float4*)&s_qout[q * 32 + i4 * 4];
            acc.x += ev.x * qv.x; acc.y += ev.y * qv.y;
            acc.z += ev.z * qv.z; acc.w += ev.w * qv.w;
        }
        float sv = (acc.x + acc.y) + (acc.z + acc.w);
        sv *= 0.17677669529663687f * __expf(-log_temp[q >> 1]);
        ao[t] = outer_mask[b * 17 + g] ? sv : NEGM;
    }
    __syncthreads();

    // ---------- Phase D: outer softmax (8 lanes per query) ----------
    {
        const int q = lane >> 3, j = lane & 7;
        float s0 = ao[q * 17 + j];
        float s1 = ao[q * 17 + j + 8];
        float s2 = (j == 0) ? ao[q * 17 + 16] : NEGM;
        float mx = fmaxf(fmaxf(s0, s1), s2);
        mx = fmaxf(mx, __shfl_xor(mx, 1));
        mx = fmaxf(mx, __shfl_xor(mx, 2));
        mx = fmaxf(mx, __shfl_xor(mx, 4));
        float e0 = __expf(s0 - mx), e1 = __expf(s1 - mx);
        float e2 = (j == 0) ? __expf(s2 - mx) : 0.f;
        float ssum = e0 + e1 + e2;
        ssum += __shfl_xor(ssum, 1);
        ssum += __shfl_xor(ssum, 2);
        ssum += __shfl_xor(ssum, 4);
        float inv = 1.f / ssum;
        ao[q * 17 + j] = e0 * inv;
        ao[q * 17 + j + 8] = e1 * inv;
        if (j == 0) ao[q * 17 + 16] = e2 * inv;
    }
    __syncthreads();

    // ---------- Phase E: pooled + per-target LayerNorm ----------
    {
        const int q = lane >> 3, dq = lane & 7;
        float4 acc = {0.f, 0.f, 0.f, 0.f};
        #pragma unroll
        for (int g = 0; g < 17; ++g) {
            float w = ao[q * 17 + g];
            fma4(acc, w, *(float4*)&enc[g * 36 + dq * 4]);
        }
        float sv = (acc.x + acc.y) + (acc.z + acc.w);
        sv += __shfl_xor(sv, 1); sv += __shfl_xor(sv, 2);
        sv += __shfl_xor(sv, 4); sv += __shfl_xor(sv, 8);
        float mu = sv * 0.015625f;
        float4 d;
        d.x = acc.x - mu; d.y = acc.y - mu; d.z = acc.z - mu; d.w = acc.w - mu;
        float v = (d.x * d.x + d.y * d.y) + (d.z * d.z + d.w * d.w);
        v += __shfl_xor(v, 1); v += __shfl_xor(v, 2);
        v += __shfl_xor(v, 4); v += __shfl_xor(v, 8);
        float rs = rsqrtf(v * 0.015625f + 1e-5f);
        float4 gam = ld4(ln_g + lane * 4);
        float4 bet = ld4(ln_b + lane * 4);
        float4 res;
        res.x = d.x * rs * gam.x + bet.x; res.y = d.y * rs * gam.y + bet.y;
        res.z = d.z * rs * gam.z + bet.z; res.w = d.w * rs * gam.w + bet.w;
        *(float4*)&hist[(size_t)b * 256 + lane * 4] = res;
    }
}

// ---------------- Kernel C: backbone + per-target heads ----------------
// 16 rows per block, 256 threads. Measured-best (~32 us) b128 version.
__global__ __launch_bounds__(256) void backbone_kernel(
    const float* __restrict__ x_static,
    const float* __restrict__ W1, const float* __restrict__ b1,
    const float* __restrict__ g1, const float* __restrict__ be1,
    const float* __restrict__ m1, const float* __restrict__ v1,
    const float* __restrict__ W2, const float* __restrict__ b2,
    const float* __restrict__ g2, const float* __restrict__ be2,
    const float* __restrict__ m2, const float* __restrict__ v2,
    const float* __restrict__ Wh1, const float* __restrict__ bh1,
    const float* __restrict__ Wh2, const float* __restrict__ bh2,
    const float* __restrict__ hist, float* __restrict__ out)
{
    __shared__ float s_x[16 * 64];
    __shared__ float s_z1[16 * 256];
    __shared__ float s_z2[16 * 132];

    const int tid = threadIdx.x;
    const int row0 = blockIdx.x * 16;

    *(float4*)&s_x[tid * 4] = ld4(x_static + (size_t)row0 * 64 + tid * 4);
    __syncthreads();

    // ---- z1 = relu(BN1(x @ W1)) : one column per thread, 16 rows ----
    {
        const int col = tid;
        float acc[16];
        #pragma unroll
        for (int r = 0; r < 16; ++r) acc[r] = 0.f;
        for (int k4 = 0; k4 < 16; ++k4) {
            float w0 = W1[(k4 * 4 + 0) * 256 + col];
            float w1 = W1[(k4 * 4 + 1) * 256 + col];
            float w2 = W1[(k4 * 4 + 2) * 256 + col];
            float w3 = W1[(k4 * 4 + 3) * 256 + col];
            #pragma unroll
            for (int r = 0; r < 16; ++r) {
                float4 xv = *(float4*)&s_x[r * 64 + k4 * 4];
                acc[r] += xv.x * w0 + xv.y * w1 + xv.z * w2 + xv.w * w3;
            }
        }
        float sc = rsqrtf(v1[col] + 1e-5f) * g1[col];
        float off = b1[col] - m1[col];
        float bb = be1[col];
        #pragma unroll
        for (int r = 0; r < 16; ++r)
            s_z1[r * 256 + col] = fmaxf((acc[r] + off) * sc + bb, 0.f);
    }
    __syncthreads();

    // ---- z2 = relu(BN2(z1 @ W2)) : col = tid&127, 8 rows per thread ----
    {
        const int col = tid & 127;
        const int r0 = (tid >> 7) * 8;
        float acc[8];
        #pragma unroll
        for (int r = 0; r < 8; ++r) acc[r] = 0.f;
        for (int k4 = 0; k4 < 64; ++k4) {
            float w0 = W2[(k4 * 4 + 0) * 128 + col];
            float w1 = W2[(k4 * 4 + 1) * 128 + col];
            float w2 = W2[(k4 * 4 + 2) * 128 + col];
            float w3 = W2[(k4 * 4 + 3) * 128 + col];
            #pragma unroll
            for (int r = 0; r < 8; ++r) {
                float4 zv = *(float4*)&s_z1[(r0 + r) * 256 + k4 * 4];
                acc[r] += zv.x * w0 + zv.y * w1 + zv.z * w2 + zv.w * w3;
            }
        }
        float sc = rsqrtf(v2[col] + 1e-5f) * g2[col];
        float off = b2[col] - m2[col];
        float bb = be2[col];
        #pragma unroll
        for (int r = 0; r < 8; ++r)
            s_z2[(r0 + r) * 132 + col] = fmaxf((acc[r] + off) * sc + bb, 0.f);
    }
    __syncthreads();

    // ---- heads: 4 lanes per (row,target), 8 hidden units each ----
    {
        const int p = tid >> 2;
        const int gl = tid & 3;
        const int row = p >> 2;
        const int tgt = p & 3;
        const int j0 = gl * 8;

        float acc[8];
        #pragma unroll
        for (int j = 0; j < 8; ++j) acc[j] = bh1[tgt * 32 + j0 + j];

        const float* w1p = Wh1 + (size_t)tgt * 192 * 32 + j0;
        for (int d4 = 0; d4 < 32; ++d4) {
            float4 zv = *(float4*)&s_z2[row * 132 + d4 * 4];
            #pragma unroll
            for (int c = 0; c < 4; ++c) {
                float v = (c == 0) ? zv.x : (c == 1) ? zv.y : (c == 2) ? zv.z : zv.w;
                float4 a = ld4(w1p + (d4 * 4 + c) * 32);
                float4 bq = ld4(w1p + (d4 * 4 + c) * 32 + 4);
                acc[0] += v * a.x;  acc[1] += v * a.y;  acc[2] += v * a.z;  acc[3] += v * a.w;
                acc[4] += v * bq.x; acc[5] += v * bq.y; acc[6] += v * bq.z; acc[7] += v * bq.w;
            }
        }
        const float* hp = hist + (size_t)(row0 + row) * 256 + tgt * 64;
        const float* w1q = w1p + 128 * 32;
        for (int d4 = 0; d4 < 16; ++d4) {
            float4 hv = ld4(hp + d4 * 4);
            #pragma unroll
            for (int c = 0; c < 4; ++c) {
                float v = (c == 0) ? hv.x : (c == 1) ? hv.y : (c == 2) ? hv.z : hv.w;
                float4 a = ld4(w1q + (d4 * 4 + c) * 32);
                float4 bq = ld4(w1q + (d4 * 4 + c) * 32 + 4);
                acc[0] += v * a.x;  acc[1] += v * a.y;  acc[2] += v * a.z;  acc[3] += v * a.w;
                acc[4] += v * bq.x; acc[5] += v * bq.y; acc[6] += v * bq.z; acc[7] += v * bq.w;
            }
        }
        float ps = 0.f;
        #pragma unroll
        for (int j = 0; j < 8; ++j) ps += fmaxf(acc[j], 0.f) * Wh2[tgt * 32 + j0 + j];
        ps += __shfl_xor(ps, 1);
        ps += __shfl_xor(ps, 2);
        if (gl == 0) out[(size_t)(row0 + row) * 4 + tgt] = fmaxf(ps + bh2[tgt], 0.f);
    }
}

extern "C" void kernel_launch(void* const* d_in, const int* in_sizes, int n_in,
                              void* d_out, int out_size, void* d_ws, size_t ws_size,
                              hipStream_t stream) {
    const float* x_static = (const float*)d_in[0];
    const float* x_kicks  = (const float*)d_in[1];
    const float* W_ke     = (const float*)d_in[2];
    const float* b_ke     = (const float*)d_in[3];
    const float* q_inner  = (const float*)d_in[4];
    const float* W_ge     = (const float*)d_in[5];
    const float* b_ge     = (const float*)d_in[6];
    const float* pos_emb  = (const float*)d_in[7];
    const float* q_outer  = (const float*)d_in[8];
    const float* log_temp = (const float*)d_in[9];
    const float* ln_g     = (const float*)d_in[10];
    const float* ln_b     = (const float*)d_in[11];
    const float* W1       = (const float*)d_in[12];
    const float* b1       = (const float*)d_in[13];
    const float* g1       = (const float*)d_in[14];
    const float* be1      = (const float*)d_in[15];
    const float* m1       = (const float*)d_in[16];
    const float* v1       = (const float*)d_in[17];
    const float* W2       = (const float*)d_in[18];
    const float* b2       = (const float*)d_in[19];
    const float* g2       = (const float*)d_in[20];
    const float* be2      = (const float*)d_in[21];
    const float* m2       = (const float*)d_in[22];
    const float* v2       = (const float*)d_in[23];
    const float* Wh1      = (const float*)d_in[24];
    const float* bh1      = (const float*)d_in[25];
    const float* Wh2      = (const float*)d_in[26];
    const float* bh2      = (const float*)d_in[27];
    const int* outer_mask = (const int*)d_in[28];
    const int* inner_mask = (const int*)d_in[29];

    float* pg   = (float*)d_ws;                       // 16384*272 floats = 17.8 MB
    float* hist = pg + (size_t)16384 * 272;           // 16384*256 floats = 16.8 MB
    float* out  = (float*)d_out;

    pool_kernel<<<(16384 * 17) / 256, 256, 0, stream>>>(
        x_kicks, W_ke, b_ke, q_inner, inner_mask, pg);

    hist_kernel<<<16384 / 2, 128, 0, stream>>>(
        pg, W_ge, b_ge, pos_emb, q_outer, log_temp, ln_g, ln_b,
        outer_mask, hist);

    backbone_kernel<<<16384 / 16, 256, 0, stream>>>(
        x_static, W1, b1, g1, be1, m1, v1, W2, b2, g2, be2, m2, v2,
        Wh1, bh1, Wh2, bh2, hist, out);
}

// Round 13
// 149.950 us; speedup vs baseline: 1.2659x; 1.2659x over previous
//
#include <hip/hip_runtime.h>
#include <math.h>

#define NEGM (-1e30f)

__device__ __forceinline__ float4 ld4(const float* p) { return *(const float4*)p; }
__device__ __forceinline__ void fma4(float4& a, float s, const float4 w) {
    a.x += s * w.x; a.y += s * w.y; a.z += s * w.z; a.w += s * w.w;
}
__device__ __forceinline__ float dot4(const float4 a, const float4 b) {
    return (a.x * b.x + a.y * b.y) + (a.z * b.z + a.w * b.w);
}
__device__ __forceinline__ void upd4(float4& p, float rm, float rw, const float4 a) {
    p.x = p.x * rm + rw * a.x; p.y = p.y * rm + rw * a.y;
    p.z = p.z * rm + rw * a.z; p.w = p.w * rm + rw * a.w;
}

// ---------------- Kernel 1: nested-attention history path ----------------
// ONE WAVE PER BLOCK (64 threads, launch_bounds 64): the compiler elides
// every s_barrier (block == wave; LDS ops are in-order within a wave), so
// phases A..E flow with zero inter-wave coupling. Phase code identical to
// the measured-best variant (R3/R10).
__global__ __launch_bounds__(64) void hist_kernel(
    const float* __restrict__ x_kicks,
    const float* __restrict__ W_ke, const float* __restrict__ b_ke,
    const float* __restrict__ q_inner,
    const float* __restrict__ W_ge, const float* __restrict__ b_ge,
    const float* __restrict__ pos_emb, const float* __restrict__ q_outer,
    const float* __restrict__ log_temp,
    const float* __restrict__ ln_g, const float* __restrict__ ln_b,
    const int* __restrict__ outer_mask, const int* __restrict__ inner_mask,
    float* __restrict__ hist)
{
    __shared__ float s_wke[256];     // W_ke [16][16]
    __shared__ float s_wge[512];     // W_ge [16][32]
    __shared__ float s_qout[256];    // q_outer [8][32]
    __shared__ float pg[17 * 20];    // per_game, stride 20
    __shared__ float enc[17 * 36];   // encoded, stride 36
    __shared__ float ao[136];        // outer scores -> weights

    const int lane = threadIdx.x;    // 0..63
    const int b    = blockIdx.x;

    // stage weights: 4 float4 loads per lane (L2-hot)
    *(float4*)&s_wke[lane * 4]  = ld4(W_ke + lane * 4);
    *(float4*)&s_wge[lane * 4]  = ld4(W_ge + lane * 4);
    *(float4*)&s_wge[256 + lane * 4] = ld4(W_ge + 256 + lane * 4);
    *(float4*)&s_qout[lane * 4] = ld4(q_outer + lane * 4);
    __syncthreads();   // single wave: compiles to waitcnt only

    // ---------- Phase A: kick encoder + inner pool (online softmax) ----------
    if (lane < 51) {
        const float* xb = x_kicks + ((size_t)b * 204 + lane * 4) * 16;
        const int4 msk = *(const int4*)(inner_mask + (size_t)b * 204 + lane * 4);

        const float4 qi0 = ld4(q_inner + 0), qi1 = ld4(q_inner + 4);
        const float4 qi2 = ld4(q_inner + 8), qi3 = ld4(q_inner + 12);
        const float4 bk0 = ld4(b_ke + 0), bk1 = ld4(b_ke + 4);
        const float4 bk2 = ld4(b_ke + 8), bk3 = ld4(b_ke + 12);

        float m = NEGM, s = 0.f;
        float4 p0 = {0,0,0,0}, p1 = p0, p2 = p0, p3 = p0;

        #pragma unroll
        for (int pp = 0; pp < 4; ++pp) {
            float xs[16];
            {
                float4 x0 = ld4(xb + pp * 16 + 0), x1 = ld4(xb + pp * 16 + 4);
                float4 x2 = ld4(xb + pp * 16 + 8), x3 = ld4(xb + pp * 16 + 12);
                xs[0]=x0.x; xs[1]=x0.y; xs[2]=x0.z; xs[3]=x0.w;
                xs[4]=x1.x; xs[5]=x1.y; xs[6]=x1.z; xs[7]=x1.w;
                xs[8]=x2.x; xs[9]=x2.y; xs[10]=x2.z; xs[11]=x2.w;
                xs[12]=x3.x; xs[13]=x3.y; xs[14]=x3.z; xs[15]=x3.w;
            }
            float4 a0 = bk0, a1 = bk1, a2 = bk2, a3 = bk3;
            #pragma unroll
            for (int i = 0; i < 16; ++i) {
                float xi = xs[i];
                fma4(a0, xi, *(float4*)&s_wke[i * 16 + 0]);
                fma4(a1, xi, *(float4*)&s_wke[i * 16 + 4]);
                fma4(a2, xi, *(float4*)&s_wke[i * 16 + 8]);
                fma4(a3, xi, *(float4*)&s_wke[i * 16 + 12]);
            }
            a0.x=fmaxf(a0.x,0.f); a0.y=fmaxf(a0.y,0.f); a0.z=fmaxf(a0.z,0.f); a0.w=fmaxf(a0.w,0.f);
            a1.x=fmaxf(a1.x,0.f); a1.y=fmaxf(a1.y,0.f); a1.z=fmaxf(a1.z,0.f); a1.w=fmaxf(a1.w,0.f);
            a2.x=fmaxf(a2.x,0.f); a2.y=fmaxf(a2.y,0.f); a2.z=fmaxf(a2.z,0.f); a2.w=fmaxf(a2.w,0.f);
            a3.x=fmaxf(a3.x,0.f); a3.y=fmaxf(a3.y,0.f); a3.z=fmaxf(a3.z,0.f); a3.w=fmaxf(a3.w,0.f);

            float sc = (dot4(a0, qi0) + dot4(a1, qi1) + dot4(a2, qi2) + dot4(a3, qi3)) * 0.25f;
            int mk = (pp == 0) ? msk.x : (pp == 1) ? msk.y : (pp == 2) ? msk.z : msk.w;

            float scm = mk ? sc : NEGM;
            float mn = fmaxf(m, scm);
            float rm = __expf(m - mn);
            float rw = mk ? __expf(sc - mn) : 0.f;
            s = s * rm + rw;
            upd4(p0, rm, rw, a0); upd4(p1, rm, rw, a1);
            upd4(p2, rm, rw, a2); upd4(p3, rm, rw, a3);
            m = mn;
        }

        // merge the 3 lanes of this game
        const int base = (lane / 3) * 3;
        float gm = fmaxf(fmaxf(__shfl(m, base), __shfl(m, base + 1)), __shfl(m, base + 2));
        float r  = __expf(m - gm);
        float sl = s * r;
        float gs = __shfl(sl, base) + __shfl(sl, base + 1) + __shfl(sl, base + 2);
        float c  = r / gs;                      // kick 0 always valid -> gs > 0
        p0.x*=c; p0.y*=c; p0.z*=c; p0.w*=c;
        p1.x*=c; p1.y*=c; p1.z*=c; p1.w*=c;
        p2.x*=c; p2.y*=c; p2.z*=c; p2.w*=c;
        p3.x*=c; p3.y*=c; p3.z*=c; p3.w*=c;

        float4 o0, o1, o2, o3;
        o0.x = __shfl(p0.x,base)+__shfl(p0.x,base+1)+__shfl(p0.x,base+2);
        o0.y = __shfl(p0.y,base)+__shfl(p0.y,base+1)+__shfl(p0.y,base+2);
        o0.z = __shfl(p0.z,base)+__shfl(p0.z,base+1)+__shfl(p0.z,base+2);
        o0.w = __shfl(p0.w,base)+__shfl(p0.w,base+1)+__shfl(p0.w,base+2);
        o1.x = __shfl(p1.x,base)+__shfl(p1.x,base+1)+__shfl(p1.x,base+2);
        o1.y = __shfl(p1.y,base)+__shfl(p1.y,base+1)+__shfl(p1.y,base+2);
        o1.z = __shfl(p1.z,base)+__shfl(p1.z,base+1)+__shfl(p1.z,base+2);
        o1.w = __shfl(p1.w,base)+__shfl(p1.w,base+1)+__shfl(p1.w,base+2);
        o2.x = __shfl(p2.x,base)+__shfl(p2.x,base+1)+__shfl(p2.x,base+2);
        o2.y = __shfl(p2.y,base)+__shfl(p2.y,base+1)+__shfl(p2.y,base+2);
        o2.z = __shfl(p2.z,base)+__shfl(p2.z,base+1)+__shfl(p2.z,base+2);
        o2.w = __shfl(p2.w,base)+__shfl(p2.w,base+1)+__shfl(p2.w,base+2);
        o3.x = __shfl(p3.x,base)+__shfl(p3.x,base+1)+__shfl(p3.x,base+2);
        o3.y = __shfl(p3.y,base)+__shfl(p3.y,base+1)+__shfl(p3.y,base+2);
        o3.z = __shfl(p3.z,base)+__shfl(p3.z,base+1)+__shfl(p3.z,base+2);
        o3.w = __shfl(p3.w,base)+__shfl(p3.w,base+1)+__shfl(p3.w,base+2);
        if (lane == base) {
            const int g = lane / 3;
            *(float4*)&pg[g * 20 + 0]  = o0;
            *(float4*)&pg[g * 20 + 4]  = o1;
            *(float4*)&pg[g * 20 + 8]  = o2;
            *(float4*)&pg[g * 20 + 12] = o3;
        }
    }
    __syncthreads();

    // ---------- Phase B: game encoder + pos emb -> enc[17][32] ----------
    for (int t = lane; t < 136; t += 64) {
        const int g = t >> 3, dq = t & 7;
        float4 acc = ld4(b_ge + dq * 4);
        #pragma unroll
        for (int i = 0; i < 16; ++i) {
            float pv = pg[g * 20 + i];
            fma4(acc, pv, *(float4*)&s_wge[i * 32 + dq * 4]);
        }
        float4 pe = ld4(pos_emb + g * 32 + dq * 4);
        acc.x = fmaxf(acc.x, 0.f) + pe.x; acc.y = fmaxf(acc.y, 0.f) + pe.y;
        acc.z = fmaxf(acc.z, 0.f) + pe.z; acc.w = fmaxf(acc.w, 0.f) + pe.w;
        *(float4*)&enc[g * 36 + dq * 4] = acc;
    }
    __syncthreads();

    // ---------- Phase C: outer attention scores ao[8][17] ----------
    for (int t = lane; t < 136; t += 64) {
        const int q = t / 17, g = t - q * 17;
        float4 acc = {0.f, 0.f, 0.f, 0.f};
        #pragma unroll
        for (int i4 = 0; i4 < 8; ++i4) {
            float4 ev = *(float4*)&enc[g * 36 + i4 * 4];
            float4 qv = *(float4*)&s_qout[q * 32 + i4 * 4];
            acc.x += ev.x * qv.x; acc.y += ev.y * qv.y;
            acc.z += ev.z * qv.z; acc.w += ev.w * qv.w;
        }
        float sv = (acc.x + acc.y) + (acc.z + acc.w);
        sv *= 0.17677669529663687f * __expf(-log_temp[q >> 1]);
        ao[t] = outer_mask[b * 17 + g] ? sv : NEGM;
    }
    __syncthreads();

    // ---------- Phase D: outer softmax (8 lanes per query) ----------
    {
        const int q = lane >> 3, j = lane & 7;
        float s0 = ao[q * 17 + j];
        float s1 = ao[q * 17 + j + 8];
        float s2 = (j == 0) ? ao[q * 17 + 16] : NEGM;
        float mx = fmaxf(fmaxf(s0, s1), s2);
        mx = fmaxf(mx, __shfl_xor(mx, 1));
        mx = fmaxf(mx, __shfl_xor(mx, 2));
        mx = fmaxf(mx, __shfl_xor(mx, 4));
        float e0 = __expf(s0 - mx), e1 = __expf(s1 - mx);
        float e2 = (j == 0) ? __expf(s2 - mx) : 0.f;
        float ssum = e0 + e1 + e2;
        ssum += __shfl_xor(ssum, 1);
        ssum += __shfl_xor(ssum, 2);
        ssum += __shfl_xor(ssum, 4);
        float inv = 1.f / ssum;
        ao[q * 17 + j] = e0 * inv;
        ao[q * 17 + j + 8] = e1 * inv;
        if (j == 0) ao[q * 17 + 16] = e2 * inv;
    }
    __syncthreads();

    // ---------- Phase E: pooled + per-target LayerNorm ----------
    {
        const int q = lane >> 3, dq = lane & 7;
        float4 acc = {0.f, 0.f, 0.f, 0.f};
        #pragma unroll
        for (int g = 0; g < 17; ++g) {
            float w = ao[q * 17 + g];
            fma4(acc, w, *(float4*)&enc[g * 36 + dq * 4]);
        }
        float sv = (acc.x + acc.y) + (acc.z + acc.w);
        sv += __shfl_xor(sv, 1); sv += __shfl_xor(sv, 2);
        sv += __shfl_xor(sv, 4); sv += __shfl_xor(sv, 8);
        float mu = sv * 0.015625f;
        float4 d;
        d.x = acc.x - mu; d.y = acc.y - mu; d.z = acc.z - mu; d.w = acc.w - mu;
        float v = (d.x * d.x + d.y * d.y) + (d.z * d.z + d.w * d.w);
        v += __shfl_xor(v, 1); v += __shfl_xor(v, 2);
        v += __shfl_xor(v, 4); v += __shfl_xor(v, 8);
        float rs = rsqrtf(v * 0.015625f + 1e-5f);
        float4 gam = ld4(ln_g + lane * 4);
        float4 bet = ld4(ln_b + lane * 4);
        float4 res;
        res.x = d.x * rs * gam.x + bet.x; res.y = d.y * rs * gam.y + bet.y;
        res.z = d.z * rs * gam.z + bet.z; res.w = d.w * rs * gam.w + bet.w;
        *(float4*)&hist[(size_t)b * 256 + lane * 4] = res;
    }
}

// ---------------- Kernel 2: backbone + per-target heads ----------------
// 16 rows per block, 256 threads. Measured-best (~32 us) b128 version.
__global__ __launch_bounds__(256) void backbone_kernel(
    const float* __restrict__ x_static,
    const float* __restrict__ W1, const float* __restrict__ b1,
    const float* __restrict__ g1, const float* __restrict__ be1,
    const float* __restrict__ m1, const float* __restrict__ v1,
    const float* __restrict__ W2, const float* __restrict__ b2,
    const float* __restrict__ g2, const float* __restrict__ be2,
    const float* __restrict__ m2, const float* __restrict__ v2,
    const float* __restrict__ Wh1, const float* __restrict__ bh1,
    const float* __restrict__ Wh2, const float* __restrict__ bh2,
    const float* __restrict__ hist, float* __restrict__ out)
{
    __shared__ float s_x[16 * 64];
    __shared__ float s_z1[16 * 256];
    __shared__ float s_z2[16 * 132];

    const int tid = threadIdx.x;
    const int row0 = blockIdx.x * 16;

    *(float4*)&s_x[tid * 4] = ld4(x_static + (size_t)row0 * 64 + tid * 4);
    __syncthreads();

    // ---- z1 = relu(BN1(x @ W1)) : one column per thread, 16 rows ----
    {
        const int col = tid;
        float acc[16];
        #pragma unroll
        for (int r = 0; r < 16; ++r) acc[r] = 0.f;
        for (int k4 = 0; k4 < 16; ++k4) {
            float w0 = W1[(k4 * 4 + 0) * 256 + col];
            float w1 = W1[(k4 * 4 + 1) * 256 + col];
            float w2 = W1[(k4 * 4 + 2) * 256 + col];
            float w3 = W1[(k4 * 4 + 3) * 256 + col];
            #pragma unroll
            for (int r = 0; r < 16; ++r) {
                float4 xv = *(float4*)&s_x[r * 64 + k4 * 4];
                acc[r] += xv.x * w0 + xv.y * w1 + xv.z * w2 + xv.w * w3;
            }
        }
        float sc = rsqrtf(v1[col] + 1e-5f) * g1[col];
        float off = b1[col] - m1[col];
        float bb = be1[col];
        #pragma unroll
        for (int r = 0; r < 16; ++r)
            s_z1[r * 256 + col] = fmaxf((acc[r] + off) * sc + bb, 0.f);
    }
    __syncthreads();

    // ---- z2 = relu(BN2(z1 @ W2)) : col = tid&127, 8 rows per thread ----
    {
        const int col = tid & 127;
        const int r0 = (tid >> 7) * 8;
        float acc[8];
        #pragma unroll
        for (int r = 0; r < 8; ++r) acc[r] = 0.f;
        for (int k4 = 0; k4 < 64; ++k4) {
            float w0 = W2[(k4 * 4 + 0) * 128 + col];
            float w1 = W2[(k4 * 4 + 1) * 128 + col];
            float w2 = W2[(k4 * 4 + 2) * 128 + col];
            float w3 = W2[(k4 * 4 + 3) * 128 + col];
            #pragma unroll
            for (int r = 0; r < 8; ++r) {
                float4 zv = *(float4*)&s_z1[(r0 + r) * 256 + k4 * 4];
                acc[r] += zv.x * w0 + zv.y * w1 + zv.z * w2 + zv.w * w3;
            }
        }
        float sc = rsqrtf(v2[col] + 1e-5f) * g2[col];
        float off = b2[col] - m2[col];
        float bb = be2[col];
        #pragma unroll
        for (int r = 0; r < 8; ++r)
            s_z2[(r0 + r) * 132 + col] = fmaxf((acc[r] + off) * sc + bb, 0.f);
    }
    __syncthreads();

    // ---- heads: 4 lanes per (row,target), 8 hidden units each ----
    {
        const int p = tid >> 2;
        const int gl = tid & 3;
        const int row = p >> 2;
        const int tgt = p & 3;
        const int j0 = gl * 8;

        float acc[8];
        #pragma unroll
        for (int j = 0; j < 8; ++j) acc[j] = bh1[tgt * 32 + j0 + j];

        const float* w1p = Wh1 + (size_t)tgt * 192 * 32 + j0;
        for (int d4 = 0; d4 < 32; ++d4) {
            float4 zv = *(float4*)&s_z2[row * 132 + d4 * 4];
            #pragma unroll
            for (int c = 0; c < 4; ++c) {
                float v = (c == 0) ? zv.x : (c == 1) ? zv.y : (c == 2) ? zv.z : zv.w;
                float4 a = ld4(w1p + (d4 * 4 + c) * 32);
                float4 bq = ld4(w1p + (d4 * 4 + c) * 32 + 4);
                acc[0] += v * a.x;  acc[1] += v * a.y;  acc[2] += v * a.z;  acc[3] += v * a.w;
                acc[4] += v * bq.x; acc[5] += v * bq.y; acc[6] += v * bq.z; acc[7] += v * bq.w;
            }
        }
        const float* hp = hist + (size_t)(row0 + row) * 256 + tgt * 64;
        const float* w1q = w1p + 128 * 32;
        for (int d4 = 0; d4 < 16; ++d4) {
            float4 hv = ld4(hp + d4 * 4);
            #pragma unroll
            for (int c = 0; c < 4; ++c) {
                float v = (c == 0) ? hv.x : (c == 1) ? hv.y : (c == 2) ? hv.z : hv.w;
                float4 a = ld4(w1q + (d4 * 4 + c) * 32);
                float4 bq = ld4(w1q + (d4 * 4 + c) * 32 + 4);
                acc[0] += v * a.x;  acc[1] += v * a.y;  acc[2] += v * a.z;  acc[3] += v * a.w;
                acc[4] += v * bq.x; acc[5] += v * bq.y; acc[6] += v * bq.z; acc[7] += v * bq.w;
            }
        }
        float ps = 0.f;
        #pragma unroll
        for (int j = 0; j < 8; ++j) ps += fmaxf(acc[j], 0.f) * Wh2[tgt * 32 + j0 + j];
        ps += __shfl_xor(ps, 1);
        ps += __shfl_xor(ps, 2);
        if (gl == 0) out[(size_t)(row0 + row) * 4 + tgt] = fmaxf(ps + bh2[tgt], 0.f);
    }
}

extern "C" void kernel_launch(void* const* d_in, const int* in_sizes, int n_in,
                              void* d_out, int out_size, void* d_ws, size_t ws_size,
                              hipStream_t stream) {
    const float* x_static = (const float*)d_in[0];
    const float* x_kicks  = (const float*)d_in[1];
    const float* W_ke     = (const float*)d_in[2];
    const float* b_ke     = (const float*)d_in[3];
    const float* q_inner  = (const float*)d_in[4];
    const float* W_ge     = (const float*)d_in[5];
    const float* b_ge     = (const float*)d_in[6];
    const float* pos_emb  = (const float*)d_in[7];
    const float* q_outer  = (const float*)d_in[8];
    const float* log_temp = (const float*)d_in[9];
    const float* ln_g     = (const float*)d_in[10];
    const float* ln_b     = (const float*)d_in[11];
    const float* W1       = (const float*)d_in[12];
    const float* b1       = (const float*)d_in[13];
    const float* g1       = (const float*)d_in[14];
    const float* be1      = (const float*)d_in[15];
    const float* m1       = (const float*)d_in[16];
    const float* v1       = (const float*)d_in[17];
    const float* W2       = (const float*)d_in[18];
    const float* b2       = (const float*)d_in[19];
    const float* g2       = (const float*)d_in[20];
    const float* be2      = (const float*)d_in[21];
    const float* m2       = (const float*)d_in[22];
    const float* v2       = (const float*)d_in[23];
    const float* Wh1      = (const float*)d_in[24];
    const float* bh1      = (const float*)d_in[25];
    const float* Wh2      = (const float*)d_in[26];
    const float* bh2      = (const float*)d_in[27];
    const int* outer_mask = (const int*)d_in[28];
    const int* inner_mask = (const int*)d_in[29];

    float* hist = (float*)d_ws;           // 16384 * 256 floats = 16.8 MB
    float* out  = (float*)d_out;

    hist_kernel<<<16384, 64, 0, stream>>>(
        x_kicks, W_ke, b_ke, q_inner, W_ge, b_ge, pos_emb, q_outer,
        log_temp, ln_g, ln_b, outer_mask, inner_mask, hist);

    backbone_kernel<<<16384 / 16, 256, 0, stream>>>(
        x_static, W1, b1, g1, be1, m1, v1, W2, b2, g2, be2, m2, v2,
        Wh1, bh1, Wh2, bh2, hist, out);
}

// Round 14
// 149.722 us; speedup vs baseline: 1.2678x; 1.0015x over previous
//
#include <hip/hip_runtime.h>
#include <math.h>

#define NEGM (-1e30f)

__device__ __forceinline__ float4 ld4(const float* p) { return *(const float4*)p; }
__device__ __forceinline__ void fma4(float4& a, float s, const float4 w) {
    a.x += s * w.x; a.y += s * w.y; a.z += s * w.z; a.w += s * w.w;
}
__device__ __forceinline__ float dot4(const float4 a, const float4 b) {
    return (a.x * b.x + a.y * b.y) + (a.z * b.z + a.w * b.w);
}
__device__ __forceinline__ void upd4(float4& p, float rm, float rw, const float4 a) {
    p.x = p.x * rm + rw * a.x; p.y = p.y * rm + rw * a.y;
    p.z = p.z * rm + rw * a.z; p.w = p.w * rm + rw * a.w;
}
__device__ __forceinline__ void relu4(float4& a) {
    a.x = fmaxf(a.x, 0.f); a.y = fmaxf(a.y, 0.f);
    a.z = fmaxf(a.z, 0.f); a.w = fmaxf(a.w, 0.f);
}

// ---------------- Kernel 1: nested-attention history path ----------------
// ONE WAVE PER BLOCK (barrier-free, R13) + 2-kick inner unroll: one set of
// W_ke LDS reads feeds FMAs for TWO kicks -> ~64 cy of issue between
// dependent lgkmcnt waits, pipelined 2-deep covers the ~120 cy ds_read
// latency within a single wave.
__global__ __launch_bounds__(64) void hist_kernel(
    const float* __restrict__ x_kicks,
    const float* __restrict__ W_ke, const float* __restrict__ b_ke,
    const float* __restrict__ q_inner,
    const float* __restrict__ W_ge, const float* __restrict__ b_ge,
    const float* __restrict__ pos_emb, const float* __restrict__ q_outer,
    const float* __restrict__ log_temp,
    const float* __restrict__ ln_g, const float* __restrict__ ln_b,
    const int* __restrict__ outer_mask, const int* __restrict__ inner_mask,
    float* __restrict__ hist)
{
    __shared__ float s_wke[256];     // W_ke [16][16]
    __shared__ float s_wge[512];     // W_ge [16][32]
    __shared__ float s_qout[256];    // q_outer [8][32]
    __shared__ float pg[17 * 20];    // per_game, stride 20
    __shared__ float enc[17 * 36];   // encoded, stride 36
    __shared__ float ao[136];        // outer scores -> weights

    const int lane = threadIdx.x;    // 0..63
    const int b    = blockIdx.x;

    // stage weights: 4 float4 loads per lane (L2-hot)
    *(float4*)&s_wke[lane * 4]  = ld4(W_ke + lane * 4);
    *(float4*)&s_wge[lane * 4]  = ld4(W_ge + lane * 4);
    *(float4*)&s_wge[256 + lane * 4] = ld4(W_ge + 256 + lane * 4);
    *(float4*)&s_qout[lane * 4] = ld4(q_outer + lane * 4);
    __syncthreads();   // single wave: waitcnt only

    // ---------- Phase A: kick encoder + inner pool (online softmax) ----------
    if (lane < 51) {
        const float* xb = x_kicks + ((size_t)b * 204 + lane * 4) * 16;
        const int4 msk = *(const int4*)(inner_mask + (size_t)b * 204 + lane * 4);

        const float4 qi0 = ld4(q_inner + 0), qi1 = ld4(q_inner + 4);
        const float4 qi2 = ld4(q_inner + 8), qi3 = ld4(q_inner + 12);
        const float4 bk0 = ld4(b_ke + 0), bk1 = ld4(b_ke + 4);
        const float4 bk2 = ld4(b_ke + 8), bk3 = ld4(b_ke + 12);

        float m = NEGM, s = 0.f;
        float4 p0 = {0,0,0,0}, p1 = p0, p2 = p0, p3 = p0;

        #pragma unroll
        for (int h = 0; h < 2; ++h) {
            // load 2 kicks' features
            float xa[16], xc[16];
            {
                const float* pa = xb + (2 * h) * 16;
                float4 t0 = ld4(pa + 0), t1 = ld4(pa + 4), t2 = ld4(pa + 8), t3 = ld4(pa + 12);
                xa[0]=t0.x; xa[1]=t0.y; xa[2]=t0.z; xa[3]=t0.w;
                xa[4]=t1.x; xa[5]=t1.y; xa[6]=t1.z; xa[7]=t1.w;
                xa[8]=t2.x; xa[9]=t2.y; xa[10]=t2.z; xa[11]=t2.w;
                xa[12]=t3.x; xa[13]=t3.y; xa[14]=t3.z; xa[15]=t3.w;
                const float* pc = xb + (2 * h + 1) * 16;
                float4 u0 = ld4(pc + 0), u1 = ld4(pc + 4), u2 = ld4(pc + 8), u3 = ld4(pc + 12);
                xc[0]=u0.x; xc[1]=u0.y; xc[2]=u0.z; xc[3]=u0.w;
                xc[4]=u1.x; xc[5]=u1.y; xc[6]=u1.z; xc[7]=u1.w;
                xc[8]=u2.x; xc[9]=u2.y; xc[10]=u2.z; xc[11]=u2.w;
                xc[12]=u3.x; xc[13]=u3.y; xc[14]=u3.z; xc[15]=u3.w;
            }
            float4 A0 = bk0, A1 = bk1, A2 = bk2, A3 = bk3;
            float4 C0 = bk0, C1 = bk1, C2 = bk2, C3 = bk3;
            #pragma unroll
            for (int i = 0; i < 16; ++i) {
                float4 w0 = *(float4*)&s_wke[i * 16 + 0];
                float4 w1 = *(float4*)&s_wke[i * 16 + 4];
                float4 w2 = *(float4*)&s_wke[i * 16 + 8];
                float4 w3 = *(float4*)&s_wke[i * 16 + 12];
                float va = xa[i], vc = xc[i];
                fma4(A0, va, w0); fma4(A1, va, w1); fma4(A2, va, w2); fma4(A3, va, w3);
                fma4(C0, vc, w0); fma4(C1, vc, w1); fma4(C2, vc, w2); fma4(C3, vc, w3);
            }
            relu4(A0); relu4(A1); relu4(A2); relu4(A3);
            relu4(C0); relu4(C1); relu4(C2); relu4(C3);

            float scA = (dot4(A0,qi0) + dot4(A1,qi1) + dot4(A2,qi2) + dot4(A3,qi3)) * 0.25f;
            float scC = (dot4(C0,qi0) + dot4(C1,qi1) + dot4(C2,qi2) + dot4(C3,qi3)) * 0.25f;
            const int mkA = h ? msk.z : msk.x;
            const int mkC = h ? msk.w : msk.y;

            {   // online update: kick A
                float scm = mkA ? scA : NEGM;
                float mn = fmaxf(m, scm);
                float rm = __expf(m - mn);
                float rw = mkA ? __expf(scA - mn) : 0.f;
                s = s * rm + rw;
                upd4(p0, rm, rw, A0); upd4(p1, rm, rw, A1);
                upd4(p2, rm, rw, A2); upd4(p3, rm, rw, A3);
                m = mn;
            }
            {   // online update: kick C
                float scm = mkC ? scC : NEGM;
                float mn = fmaxf(m, scm);
                float rm = __expf(m - mn);
                float rw = mkC ? __expf(scC - mn) : 0.f;
                s = s * rm + rw;
                upd4(p0, rm, rw, C0); upd4(p1, rm, rw, C1);
                upd4(p2, rm, rw, C2); upd4(p3, rm, rw, C3);
                m = mn;
            }
        }

        // merge the 3 lanes of this game
        const int base = (lane / 3) * 3;
        float gm = fmaxf(fmaxf(__shfl(m, base), __shfl(m, base + 1)), __shfl(m, base + 2));
        float r  = __expf(m - gm);
        float sl = s * r;
        float gs = __shfl(sl, base) + __shfl(sl, base + 1) + __shfl(sl, base + 2);
        float c  = r / gs;                      // kick 0 always valid -> gs > 0
        p0.x*=c; p0.y*=c; p0.z*=c; p0.w*=c;
        p1.x*=c; p1.y*=c; p1.z*=c; p1.w*=c;
        p2.x*=c; p2.y*=c; p2.z*=c; p2.w*=c;
        p3.x*=c; p3.y*=c; p3.z*=c; p3.w*=c;

        float4 o0, o1, o2, o3;
        o0.x = __shfl(p0.x,base)+__shfl(p0.x,base+1)+__shfl(p0.x,base+2);
        o0.y = __shfl(p0.y,base)+__shfl(p0.y,base+1)+__shfl(p0.y,base+2);
        o0.z = __shfl(p0.z,base)+__shfl(p0.z,base+1)+__shfl(p0.z,base+2);
        o0.w = __shfl(p0.w,base)+__shfl(p0.w,base+1)+__shfl(p0.w,base+2);
        o1.x = __shfl(p1.x,base)+__shfl(p1.x,base+1)+__shfl(p1.x,base+2);
        o1.y = __shfl(p1.y,base)+__shfl(p1.y,base+1)+__shfl(p1.y,base+2);
        o1.z = __shfl(p1.z,base)+__shfl(p1.z,base+1)+__shfl(p1.z,base+2);
        o1.w = __shfl(p1.w,base)+__shfl(p1.w,base+1)+__shfl(p1.w,base+2);
        o2.x = __shfl(p2.x,base)+__shfl(p2.x,base+1)+__shfl(p2.x,base+2);
        o2.y = __shfl(p2.y,base)+__shfl(p2.y,base+1)+__shfl(p2.y,base+2);
        o2.z = __shfl(p2.z,base)+__shfl(p2.z,base+1)+__shfl(p2.z,base+2);
        o2.w = __shfl(p2.w,base)+__shfl(p2.w,base+1)+__shfl(p2.w,base+2);
        o3.x = __shfl(p3.x,base)+__shfl(p3.x,base+1)+__shfl(p3.x,base+2);
        o3.y = __shfl(p3.y,base)+__shfl(p3.y,base+1)+__shfl(p3.y,base+2);
        o3.z = __shfl(p3.z,base)+__shfl(p3.z,base+1)+__shfl(p3.z,base+2);
        o3.w = __shfl(p3.w,base)+__shfl(p3.w,base+1)+__shfl(p3.w,base+2);
        if (lane == base) {
            const int g = lane / 3;
            *(float4*)&pg[g * 20 + 0]  = o0;
            *(float4*)&pg[g * 20 + 4]  = o1;
            *(float4*)&pg[g * 20 + 8]  = o2;
            *(float4*)&pg[g * 20 + 12] = o3;
        }
    }
    __syncthreads();

    // ---------- Phase B: game encoder + pos emb -> enc[17][32] ----------
    for (int t = lane; t < 136; t += 64) {
        const int g = t >> 3, dq = t & 7;
        float4 acc = ld4(b_ge + dq * 4);
        #pragma unroll
        for (int i = 0; i < 16; ++i) {
            float pv = pg[g * 20 + i];
            fma4(acc, pv, *(float4*)&s_wge[i * 32 + dq * 4]);
        }
        float4 pe = ld4(pos_emb + g * 32 + dq * 4);
        acc.x = fmaxf(acc.x, 0.f) + pe.x; acc.y = fmaxf(acc.y, 0.f) + pe.y;
        acc.z = fmaxf(acc.z, 0.f) + pe.z; acc.w = fmaxf(acc.w, 0.f) + pe.w;
        *(float4*)&enc[g * 36 + dq * 4] = acc;
    }
    __syncthreads();

    // ---------- Phase C: outer attention scores ao[8][17] ----------
    for (int t = lane; t < 136; t += 64) {
        const int q = t / 17, g = t - q * 17;
        float4 acc = {0.f, 0.f, 0.f, 0.f};
        #pragma unroll
        for (int i4 = 0; i4 < 8; ++i4) {
            float4 ev = *(float4*)&enc[g * 36 + i4 * 4];
            float4 qv = *(float4*)&s_qout[q * 32 + i4 * 4];
            acc.x += ev.x * qv.x; acc.y += ev.y * qv.y;
            acc.z += ev.z * qv.z; acc.w += ev.w * qv.w;
        }
        float sv = (acc.x + acc.y) + (acc.z + acc.w);
        sv *= 0.17677669529663687f * __expf(-log_temp[q >> 1]);
        ao[t] = outer_mask[b * 17 + g] ? sv : NEGM;
    }
    __syncthreads();

    // ---------- Phase D: outer softmax (8 lanes per query) ----------
    {
        const int q = lane >> 3, j = lane & 7;
        float s0 = ao[q * 17 + j];
        float s1 = ao[q * 17 + j + 8];
        float s2 = (j == 0) ? ao[q * 17 + 16] : NEGM;
        float mx = fmaxf(fmaxf(s0, s1), s2);
        mx = fmaxf(mx, __shfl_xor(mx, 1));
        mx = fmaxf(mx, __shfl_xor(mx, 2));
        mx = fmaxf(mx, __shfl_xor(mx, 4));
        float e0 = __expf(s0 - mx), e1 = __expf(s1 - mx);
        float e2 = (j == 0) ? __expf(s2 - mx) : 0.f;
        float ssum = e0 + e1 + e2;
        ssum += __shfl_xor(ssum, 1);
        ssum += __shfl_xor(ssum, 2);
        ssum += __shfl_xor(ssum, 4);
        float inv = 1.f / ssum;
        ao[q * 17 + j] = e0 * inv;
        ao[q * 17 + j + 8] = e1 * inv;
        if (j == 0) ao[q * 17 + 16] = e2 * inv;
    }
    __syncthreads();

    // ---------- Phase E: pooled + per-target LayerNorm ----------
    {
        const int q = lane >> 3, dq = lane & 7;
        float4 acc = {0.f, 0.f, 0.f, 0.f};
        #pragma unroll
        for (int g = 0; g < 17; ++g) {
            float w = ao[q * 17 + g];
            fma4(acc, w, *(float4*)&enc[g * 36 + dq * 4]);
        }
        float sv = (acc.x + acc.y) + (acc.z + acc.w);
        sv += __shfl_xor(sv, 1); sv += __shfl_xor(sv, 2);
        sv += __shfl_xor(sv, 4); sv += __shfl_xor(sv, 8);
        float mu = sv * 0.015625f;
        float4 d;
        d.x = acc.x - mu; d.y = acc.y - mu; d.z = acc.z - mu; d.w = acc.w - mu;
        float v = (d.x * d.x + d.y * d.y) + (d.z * d.z + d.w * d.w);
        v += __shfl_xor(v, 1); v += __shfl_xor(v, 2);
        v += __shfl_xor(v, 4); v += __shfl_xor(v, 8);
        float rs = rsqrtf(v * 0.015625f + 1e-5f);
        float4 gam = ld4(ln_g + lane * 4);
        float4 bet = ld4(ln_b + lane * 4);
        float4 res;
        res.x = d.x * rs * gam.x + bet.x; res.y = d.y * rs * gam.y + bet.y;
        res.z = d.z * rs * gam.z + bet.z; res.w = d.w * rs * gam.w + bet.w;
        *(float4*)&hist[(size_t)b * 256 + lane * 4] = res;
    }
}

// ---------------- Kernel 2: backbone + per-target heads ----------------
// 16 rows per block, 256 threads. Measured-best (~32 us) b128 version.
__global__ __launch_bounds__(256) void backbone_kernel(
    const float* __restrict__ x_static,
    const float* __restrict__ W1, const float* __restrict__ b1,
    const float* __restrict__ g1, const float* __restrict__ be1,
    const float* __restrict__ m1, const float* __restrict__ v1,
    const float* __restrict__ W2, const float* __restrict__ b2,
    const float* __restrict__ g2, const float* __restrict__ be2,
    const float* __restrict__ m2, const float* __restrict__ v2,
    const float* __restrict__ Wh1, const float* __restrict__ bh1,
    const float* __restrict__ Wh2, const float* __restrict__ bh2,
    const float* __restrict__ hist, float* __restrict__ out)
{
    __shared__ float s_x[16 * 64];
    __shared__ float s_z1[16 * 256];
    __shared__ float s_z2[16 * 132];

    const int tid = threadIdx.x;
    const int row0 = blockIdx.x * 16;

    *(float4*)&s_x[tid * 4] = ld4(x_static + (size_t)row0 * 64 + tid * 4);
    __syncthreads();

    // ---- z1 = relu(BN1(x @ W1)) : one column per thread, 16 rows ----
    {
        const int col = tid;
        float acc[16];
        #pragma unroll
        for (int r = 0; r < 16; ++r) acc[r] = 0.f;
        for (int k4 = 0; k4 < 16; ++k4) {
            float w0 = W1[(k4 * 4 + 0) * 256 + col];
            float w1 = W1[(k4 * 4 + 1) * 256 + col];
            float w2 = W1[(k4 * 4 + 2) * 256 + col];
            float w3 = W1[(k4 * 4 + 3) * 256 + col];
            #pragma unroll
            for (int r = 0; r < 16; ++r) {
                float4 xv = *(float4*)&s_x[r * 64 + k4 * 4];
                acc[r] += xv.x * w0 + xv.y * w1 + xv.z * w2 + xv.w * w3;
            }
        }
        float sc = rsqrtf(v1[col] + 1e-5f) * g1[col];
        float off = b1[col] - m1[col];
        float bb = be1[col];
        #pragma unroll
        for (int r = 0; r < 16; ++r)
            s_z1[r * 256 + col] = fmaxf((acc[r] + off) * sc + bb, 0.f);
    }
    __syncthreads();

    // ---- z2 = relu(BN2(z1 @ W2)) : col = tid&127, 8 rows per thread ----
    {
        const int col = tid & 127;
        const int r0 = (tid >> 7) * 8;
        float acc[8];
        #pragma unroll
        for (int r = 0; r < 8; ++r) acc[r] = 0.f;
        for (int k4 = 0; k4 < 64; ++k4) {
            float w0 = W2[(k4 * 4 + 0) * 128 + col];
            float w1 = W2[(k4 * 4 + 1) * 128 + col];
            float w2 = W2[(k4 * 4 + 2) * 128 + col];
            float w3 = W2[(k4 * 4 + 3) * 128 + col];
            #pragma unroll
            for (int r = 0; r < 8; ++r) {
                float4 zv = *(float4*)&s_z1[(r0 + r) * 256 + k4 * 4];
                acc[r] += zv.x * w0 + zv.y * w1 + zv.z * w2 + zv.w * w3;
            }
        }
        float sc = rsqrtf(v2[col] + 1e-5f) * g2[col];
        float off = b2[col] - m2[col];
        float bb = be2[col];
        #pragma unroll
        for (int r = 0; r < 8; ++r)
            s_z2[(r0 + r) * 132 + col] = fmaxf((acc[r] + off) * sc + bb, 0.f);
    }
    __syncthreads();

    // ---- heads: 4 lanes per (row,target), 8 hidden units each ----
    {
        const int p = tid >> 2;
        const int gl = tid & 3;
        const int row = p >> 2;
        const int tgt = p & 3;
        const int j0 = gl * 8;

        float acc[8];
        #pragma unroll
        for (int j = 0; j < 8; ++j) acc[j] = bh1[tgt * 32 + j0 + j];

        const float* w1p = Wh1 + (size_t)tgt * 192 * 32 + j0;
        for (int d4 = 0; d4 < 32; ++d4) {
            float4 zv = *(float4*)&s_z2[row * 132 + d4 * 4];
            #pragma unroll
            for (int c = 0; c < 4; ++c) {
                float v = (c == 0) ? zv.x : (c == 1) ? zv.y : (c == 2) ? zv.z : zv.w;
                float4 a = ld4(w1p + (d4 * 4 + c) * 32);
                float4 bq = ld4(w1p + (d4 * 4 + c) * 32 + 4);
                acc[0] += v * a.x;  acc[1] += v * a.y;  acc[2] += v * a.z;  acc[3] += v * a.w;
                acc[4] += v * bq.x; acc[5] += v * bq.y; acc[6] += v * bq.z; acc[7] += v * bq.w;
            }
        }
        const float* hp = hist + (size_t)(row0 + row) * 256 + tgt * 64;
        const float* w1q = w1p + 128 * 32;
        for (int d4 = 0; d4 < 16; ++d4) {
            float4 hv = ld4(hp + d4 * 4);
            #pragma unroll
            for (int c = 0; c < 4; ++c) {
                float v = (c == 0) ? hv.x : (c == 1) ? hv.y : (c == 2) ? hv.z : hv.w;
                float4 a = ld4(w1q + (d4 * 4 + c) * 32);
                float4 bq = ld4(w1q + (d4 * 4 + c) * 32 + 4);
                acc[0] += v * a.x;  acc[1] += v * a.y;  acc[2] += v * a.z;  acc[3] += v * a.w;
                acc[4] += v * bq.x; acc[5] += v * bq.y; acc[6] += v * bq.z; acc[7] += v * bq.w;
            }
        }
        float ps = 0.f;
        #pragma unroll
        for (int j = 0; j < 8; ++j) ps += fmaxf(acc[j], 0.f) * Wh2[tgt * 32 + j0 + j];
        ps += __shfl_xor(ps, 1);
        ps += __shfl_xor(ps, 2);
        if (gl == 0) out[(size_t)(row0 + row) * 4 + tgt] = fmaxf(ps + bh2[tgt], 0.f);
    }
}

extern "C" void kernel_launch(void* const* d_in, const int* in_sizes, int n_in,
                              void* d_out, int out_size, void* d_ws, size_t ws_size,
                              hipStream_t stream) {
    const float* x_static = (const float*)d_in[0];
    const float* x_kicks  = (const float*)d_in[1];
    const float* W_ke     = (const float*)d_in[2];
    const float* b_ke     = (const float*)d_in[3];
    const float* q_inner  = (const float*)d_in[4];
    const float* W_ge     = (const float*)d_in[5];
    const float* b_ge     = (const float*)d_in[6];
    const float* pos_emb  = (const float*)d_in[7];
    const float* q_outer  = (const float*)d_in[8];
    const float* log_temp = (const float*)d_in[9];
    const float* ln_g     = (const float*)d_in[10];
    const float* ln_b     = (const float*)d_in[11];
    const float* W1       = (const float*)d_in[12];
    const float* b1       = (const float*)d_in[13];
    const float* g1       = (const float*)d_in[14];
    const float* be1      = (const float*)d_in[15];
    const float* m1       = (const float*)d_in[16];
    const float* v1       = (const float*)d_in[17];
    const float* W2       = (const float*)d_in[18];
    const float* b2       = (const float*)d_in[19];
    const float* g2       = (const float*)d_in[20];
    const float* be2      = (const float*)d_in[21];
    const float* m2       = (const float*)d_in[22];
    const float* v2       = (const float*)d_in[23];
    const float* Wh1      = (const float*)d_in[24];
    const float* bh1      = (const float*)d_in[25];
    const float* Wh2      = (const float*)d_in[26];
    const float* bh2      = (const float*)d_in[27];
    const int* outer_mask = (const int*)d_in[28];
    const int* inner_mask = (const int*)d_in[29];

    float* hist = (float*)d_ws;           // 16384 * 256 floats = 16.8 MB
    float* out  = (float*)d_out;

    hist_kernel<<<16384, 64, 0, stream>>>(
        x_kicks, W_ke, b_ke, q_inner, W_ge, b_ge, pos_emb, q_outer,
        log_temp, ln_g, ln_b, outer_mask, inner_mask, hist);

    backbone_kernel<<<16384 / 16, 256, 0, stream>>>(
        x_static, W1, b1, g1, be1, m1, v1, W2, b2, g2, be2, m2, v2,
        Wh1, bh1, Wh2, bh2, hist, out);
}

// Round 15
// 145.479 us; speedup vs baseline: 1.3048x; 1.0292x over previous
//
#include <hip/hip_runtime.h>
#include <math.h>

#define NEGM (-1e30f)

typedef __fp16 f16x4 __attribute__((ext_vector_type(4)));
typedef __fp16 f16x2 __attribute__((ext_vector_type(2)));
typedef float  f32x4 __attribute__((ext_vector_type(4)));

__device__ __forceinline__ float4 ld4(const float* p) { return *(const float4*)p; }
__device__ __forceinline__ void fma4(float4& a, float s, const float4 w) {
    a.x += s * w.x; a.y += s * w.y; a.z += s * w.z; a.w += s * w.w;
}

// ---------------- Kernel 1: nested-attention history path ----------------
// One wave per row. Phase A uses MFMA 16x16x16 f16:
//   encode: D1 = A_x @ B_W + bias  (B_W in registers, 13 tiles of 16 kicks)
//   pool:   PG += A_w @ B_enc      (B_enc = relu(D1) register-direct chain)
// Games 0-15 = kicks 0-191 = tiles 0-11; game 16 = kicks 192-203 = tile 12.
__global__ __launch_bounds__(64) void hist_kernel(
    const float* __restrict__ x_kicks,
    const float* __restrict__ W_ke, const float* __restrict__ b_ke,
    const float* __restrict__ q_inner,
    const float* __restrict__ W_ge, const float* __restrict__ b_ge,
    const float* __restrict__ pos_emb, const float* __restrict__ q_outer,
    const float* __restrict__ log_temp,
    const float* __restrict__ ln_g, const float* __restrict__ ln_b,
    const int* __restrict__ outer_mask, const int* __restrict__ inner_mask,
    float* __restrict__ hist)
{
    __shared__ float s_wge[512];     // W_ge [16][32]
    __shared__ float s_qout[256];    // q_outer [8][32]
    __shared__ float pg[17 * 20];    // per_game, stride 20
    __shared__ float enc[17 * 36];   // encoded, stride 36
    __shared__ float ao[136];        // outer scores -> weights
    __shared__ float s_S[20];        // per-game softmax denominators

    const int lane = threadIdx.x;    // 0..63
    const int b    = blockIdx.x;
    const int jcol = lane & 15;      // MFMA col (= output feature j) / A-row sel
    const int g    = lane >> 4;      // k-group
    const int kb   = g * 4;          // k base within fragments

    // stage B-E weights
    *(float4*)&s_wge[lane * 4]       = ld4(W_ge + lane * 4);
    *(float4*)&s_wge[256 + lane * 4] = ld4(W_ge + 256 + lane * 4);
    *(float4*)&s_qout[lane * 4]      = ld4(q_outer + lane * 4);

    // ---- per-lane constant fragments ----
    f16x4 bw;                         // B_W[k=kb+jj][j=jcol]
    #pragma unroll
    for (int jj = 0; jj < 4; ++jj)
        bw[jj] = (__fp16)W_ke[(kb + jj) * 16 + jcol];
    const float bias = b_ke[jcol];
    const f32x4 cinit = {bias, bias, bias, bias};
    const float qv = q_inner[jcol];

    const float* xb = x_kicks + (size_t)b * 204 * 16;
    const int*   mb = inner_mask + (size_t)b * 204;

    f32x4 PG   = {0.f, 0.f, 0.f, 0.f};
    f32x4 PG16 = {0.f, 0.f, 0.f, 0.f};
    float Sacc = 0.f, S16 = 0.f;

    // ---------- tiles 0..11 : games 0..15 ----------
    #pragma unroll
    for (int t = 0; t < 12; ++t) {
        // A_x: x[kick=16t+jcol][kb..kb+3] -> f16
        float4 xv = ld4(xb + (16 * t + jcol) * 16 + kb);
        f16x2 xlo = __builtin_amdgcn_cvt_pkrtz(xv.x, xv.y);
        f16x2 xhi = __builtin_amdgcn_cvt_pkrtz(xv.z, xv.w);
        f16x4 ax; ax[0] = xlo[0]; ax[1] = xlo[1]; ax[2] = xhi[0]; ax[3] = xhi[1];

        int4 mv = *(const int4*)(mb + 16 * t + 4 * g);   // masks kicks 16t+4g..+3

        f32x4 D1 = __builtin_amdgcn_mfma_f32_16x16x16f16(ax, bw, cinit, 0, 0, 0);
        #pragma unroll
        for (int jj = 0; jj < 4; ++jj) D1[jj] = fmaxf(D1[jj], 0.f);

        // scores for kicks 16t+4g+jj : reduce over j (16-lane group butterfly)
        f32x4 ps;
        #pragma unroll
        for (int jj = 0; jj < 4; ++jj) ps[jj] = D1[jj] * qv;
        #pragma unroll
        for (int o = 1; o < 16; o <<= 1) {
            ps[0] += __shfl_xor(ps[0], o);
            ps[1] += __shfl_xor(ps[1], o);
            ps[2] += __shfl_xor(ps[2], o);
            ps[3] += __shfl_xor(ps[3], o);
        }

        // pooling weights: row jcol = game index
        f16x4 aw;
        #pragma unroll
        for (int jj = 0; jj < 4; ++jj) {
            int kk = 16 * t + 4 * g + jj;
            int mk = (jj == 0) ? mv.x : (jj == 1) ? mv.y : (jj == 2) ? mv.z : mv.w;
            float e = mk ? __expf(ps[jj] * 0.25f) : 0.f;   // scores tiny: no max-sub needed
            float w = (kk / 12 == jcol) ? e : 0.f;
            aw[jj] = (__fp16)w;
            Sacc += w;
        }

        // B_enc = relu(D1) in f16 (register-direct D->B chain)
        f16x2 elo = __builtin_amdgcn_cvt_pkrtz(D1[0], D1[1]);
        f16x2 ehi = __builtin_amdgcn_cvt_pkrtz(D1[2], D1[3]);
        f16x4 be; be[0] = elo[0]; be[1] = elo[1]; be[2] = ehi[0]; be[3] = ehi[1];

        PG = __builtin_amdgcn_mfma_f32_16x16x16f16(aw, be, PG, 0, 0, 0);
    }

    // ---------- tile 12 : game 16 (kicks 192..203) ----------
    {
        int kidx = 192 + jcol;
        int kc = (kidx < 204) ? kidx : 203;              // clamp pad lanes
        float4 xv = ld4(xb + kc * 16 + kb);
        f16x2 xlo = __builtin_amdgcn_cvt_pkrtz(xv.x, xv.y);
        f16x2 xhi = __builtin_amdgcn_cvt_pkrtz(xv.z, xv.w);
        f16x4 ax; ax[0] = xlo[0]; ax[1] = xlo[1]; ax[2] = xhi[0]; ax[3] = xhi[1];

        int km = 192 + 4 * g;
        int kmc = (km <= 200) ? km : 200;                // clamp int4 mask load
        int4 mv = *(const int4*)(mb + kmc);

        f32x4 D1 = __builtin_amdgcn_mfma_f32_16x16x16f16(ax, bw, cinit, 0, 0, 0);
        #pragma unroll
        for (int jj = 0; jj < 4; ++jj) D1[jj] = fmaxf(D1[jj], 0.f);

        f32x4 ps;
        #pragma unroll
        for (int jj = 0; jj < 4; ++jj) ps[jj] = D1[jj] * qv;
        #pragma unroll
        for (int o = 1; o < 16; o <<= 1) {
            ps[0] += __shfl_xor(ps[0], o);
            ps[1] += __shfl_xor(ps[1], o);
            ps[2] += __shfl_xor(ps[2], o);
            ps[3] += __shfl_xor(ps[3], o);
        }

        f16x4 aw2;
        #pragma unroll
        for (int jj = 0; jj < 4; ++jj) {
            int pos = 4 * g + jj;                        // kick pos within game 16
            int mk = (jj == 0) ? mv.x : (jj == 1) ? mv.y : (jj == 2) ? mv.z : mv.w;
            bool valid = (pos < 12) && mk;
            float e = valid ? __expf(ps[jj] * 0.25f) : 0.f;
            float w = (jcol == 0) ? e : 0.f;             // single output row 0
            aw2[jj] = (__fp16)w;
            S16 += w;
        }

        f16x2 elo = __builtin_amdgcn_cvt_pkrtz(D1[0], D1[1]);
        f16x2 ehi = __builtin_amdgcn_cvt_pkrtz(D1[2], D1[3]);
        f16x4 be; be[0] = elo[0]; be[1] = elo[1]; be[2] = ehi[0]; be[3] = ehi[1];

        PG16 = __builtin_amdgcn_mfma_f32_16x16x16f16(aw2, be, PG16, 0, 0, 0);
    }

    // ---------- softmax denominators & per_game write ----------
    Sacc += __shfl_xor(Sacc, 16);
    Sacc += __shfl_xor(Sacc, 32);        // all lanes: S[game=jcol]
    S16 += __shfl_xor(S16, 16);
    S16 += __shfl_xor(S16, 32);          // lanes with jcol==0 hold S16

    if (lane < 16) s_S[lane] = Sacc;     // S[0..15]
    if (lane == 0) s_S[16] = S16;
    __syncthreads();

    #pragma unroll
    for (int jj = 0; jj < 4; ++jj) {
        int game = kb + jj;              // PG row = (lane>>4)*4+jj
        pg[game * 20 + jcol] = PG[jj] * (1.f / s_S[game]);
    }
    if (lane < 16) pg[16 * 20 + lane] = PG16[0] * (1.f / s_S[16]);
    __syncthreads();

    // ---------- Phase B: game encoder + pos emb -> enc[17][32] ----------
    for (int t = lane; t < 136; t += 64) {
        const int gg = t >> 3, dq = t & 7;
        float4 acc = ld4(b_ge + dq * 4);
        #pragma unroll
        for (int i = 0; i < 16; ++i) {
            float pv = pg[gg * 20 + i];
            fma4(acc, pv, *(float4*)&s_wge[i * 32 + dq * 4]);
        }
        float4 pe = ld4(pos_emb + gg * 32 + dq * 4);
        acc.x = fmaxf(acc.x, 0.f) + pe.x; acc.y = fmaxf(acc.y, 0.f) + pe.y;
        acc.z = fmaxf(acc.z, 0.f) + pe.z; acc.w = fmaxf(acc.w, 0.f) + pe.w;
        *(float4*)&enc[gg * 36 + dq * 4] = acc;
    }
    __syncthreads();

    // ---------- Phase C: outer attention scores ao[8][17] ----------
    for (int t = lane; t < 136; t += 64) {
        const int q = t / 17, gg = t - q * 17;
        float4 acc = {0.f, 0.f, 0.f, 0.f};
        #pragma unroll
        for (int i4 = 0; i4 < 8; ++i4) {
            float4 ev = *(float4*)&enc[gg * 36 + i4 * 4];
            float4 qvv = *(float4*)&s_qout[q * 32 + i4 * 4];
            acc.x += ev.x * qvv.x; acc.y += ev.y * qvv.y;
            acc.z += ev.z * qvv.z; acc.w += ev.w * qvv.w;
        }
        float sv = (acc.x + acc.y) + (acc.z + acc.w);
        sv *= 0.17677669529663687f * __expf(-log_temp[q >> 1]);
        ao[t] = outer_mask[b * 17 + gg] ? sv : NEGM;
    }
    __syncthreads();

    // ---------- Phase D: outer softmax (8 lanes per query) ----------
    {
        const int q = lane >> 3, j = lane & 7;
        float s0 = ao[q * 17 + j];
        float s1 = ao[q * 17 + j + 8];
        float s2 = (j == 0) ? ao[q * 17 + 16] : NEGM;
        float mx = fmaxf(fmaxf(s0, s1), s2);
        mx = fmaxf(mx, __shfl_xor(mx, 1));
        mx = fmaxf(mx, __shfl_xor(mx, 2));
        mx = fmaxf(mx, __shfl_xor(mx, 4));
        float e0 = __expf(s0 - mx), e1 = __expf(s1 - mx);
        float e2 = (j == 0) ? __expf(s2 - mx) : 0.f;
        float ssum = e0 + e1 + e2;
        ssum += __shfl_xor(ssum, 1);
        ssum += __shfl_xor(ssum, 2);
        ssum += __shfl_xor(ssum, 4);
        float inv = 1.f / ssum;
        ao[q * 17 + j] = e0 * inv;
        ao[q * 17 + j + 8] = e1 * inv;
        if (j == 0) ao[q * 17 + 16] = e2 * inv;
    }
    __syncthreads();

    // ---------- Phase E: pooled + per-target LayerNorm ----------
    {
        const int q = lane >> 3, dq = lane & 7;
        float4 acc = {0.f, 0.f, 0.f, 0.f};
        #pragma unroll
        for (int gg = 0; gg < 17; ++gg) {
            float w = ao[q * 17 + gg];
            fma4(acc, w, *(float4*)&enc[gg * 36 + dq * 4]);
        }
        float sv = (acc.x + acc.y) + (acc.z + acc.w);
        sv += __shfl_xor(sv, 1); sv += __shfl_xor(sv, 2);
        sv += __shfl_xor(sv, 4); sv += __shfl_xor(sv, 8);
        float mu = sv * 0.015625f;
        float4 d;
        d.x = acc.x - mu; d.y = acc.y - mu; d.z = acc.z - mu; d.w = acc.w - mu;
        float v = (d.x * d.x + d.y * d.y) + (d.z * d.z + d.w * d.w);
        v += __shfl_xor(v, 1); v += __shfl_xor(v, 2);
        v += __shfl_xor(v, 4); v += __shfl_xor(v, 8);
        float rs = rsqrtf(v * 0.015625f + 1e-5f);
        float4 gam = ld4(ln_g + lane * 4);
        float4 bet = ld4(ln_b + lane * 4);
        float4 res;
        res.x = d.x * rs * gam.x + bet.x; res.y = d.y * rs * gam.y + bet.y;
        res.z = d.z * rs * gam.z + bet.z; res.w = d.w * rs * gam.w + bet.w;
        *(float4*)&hist[(size_t)b * 256 + lane * 4] = res;
    }
}

// ---------------- Kernel 2: backbone + per-target heads ----------------
// 16 rows per block, 256 threads. Measured-best (~32 us) b128 version.
__global__ __launch_bounds__(256) void backbone_kernel(
    const float* __restrict__ x_static,
    const float* __restrict__ W1, const float* __restrict__ b1,
    const float* __restrict__ g1, const float* __restrict__ be1,
    const float* __restrict__ m1, const float* __restrict__ v1,
    const float* __restrict__ W2, const float* __restrict__ b2,
    const float* __restrict__ g2, const float* __restrict__ be2,
    const float* __restrict__ m2, const float* __restrict__ v2,
    const float* __restrict__ Wh1, const float* __restrict__ bh1,
    const float* __restrict__ Wh2, const float* __restrict__ bh2,
    const float* __restrict__ hist, float* __restrict__ out)
{
    __shared__ float s_x[16 * 64];
    __shared__ float s_z1[16 * 256];
    __shared__ float s_z2[16 * 132];

    const int tid = threadIdx.x;
    const int row0 = blockIdx.x * 16;

    *(float4*)&s_x[tid * 4] = ld4(x_static + (size_t)row0 * 64 + tid * 4);
    __syncthreads();

    {
        const int col = tid;
        float acc[16];
        #pragma unroll
        for (int r = 0; r < 16; ++r) acc[r] = 0.f;
        for (int k4 = 0; k4 < 16; ++k4) {
            float w0 = W1[(k4 * 4 + 0) * 256 + col];
            float w1 = W1[(k4 * 4 + 1) * 256 + col];
            float w2 = W1[(k4 * 4 + 2) * 256 + col];
            float w3 = W1[(k4 * 4 + 3) * 256 + col];
            #pragma unroll
            for (int r = 0; r < 16; ++r) {
                float4 xv = *(float4*)&s_x[r * 64 + k4 * 4];
                acc[r] += xv.x * w0 + xv.y * w1 + xv.z * w2 + xv.w * w3;
            }
        }
        float sc = rsqrtf(v1[col] + 1e-5f) * g1[col];
        float off = b1[col] - m1[col];
        float bb = be1[col];
        #pragma unroll
        for (int r = 0; r < 16; ++r)
            s_z1[r * 256 + col] = fmaxf((acc[r] + off) * sc + bb, 0.f);
    }
    __syncthreads();

    {
        const int col = tid & 127;
        const int r0 = (tid >> 7) * 8;
        float acc[8];
        #pragma unroll
        for (int r = 0; r < 8; ++r) acc[r] = 0.f;
        for (int k4 = 0; k4 < 64; ++k4) {
            float w0 = W2[(k4 * 4 + 0) * 128 + col];
            float w1 = W2[(k4 * 4 + 1) * 128 + col];
            float w2 = W2[(k4 * 4 + 2) * 128 + col];
            float w3 = W2[(k4 * 4 + 3) * 128 + col];
            #pragma unroll
            for (int r = 0; r < 8; ++r) {
                float4 zv = *(float4*)&s_z1[(r0 + r) * 256 + k4 * 4];
                acc[r] += zv.x * w0 + zv.y * w1 + zv.z * w2 + zv.w * w3;
            }
        }
        float sc = rsqrtf(v2[col] + 1e-5f) * g2[col];
        float off = b2[col] - m2[col];
        float bb = be2[col];
        #pragma unroll
        for (int r = 0; r < 8; ++r)
            s_z2[(r0 + r) * 132 + col] = fmaxf((acc[r] + off) * sc + bb, 0.f);
    }
    __syncthreads();

    {
        const int p = tid >> 2;
        const int gl = tid & 3;
        const int row = p >> 2;
        const int tgt = p & 3;
        const int j0 = gl * 8;

        float acc[8];
        #pragma unroll
        for (int j = 0; j < 8; ++j) acc[j] = bh1[tgt * 32 + j0 + j];

        const float* w1p = Wh1 + (size_t)tgt * 192 * 32 + j0;
        for (int d4 = 0; d4 < 32; ++d4) {
            float4 zv = *(float4*)&s_z2[row * 132 + d4 * 4];
            #pragma unroll
            for (int c = 0; c < 4; ++c) {
                float v = (c == 0) ? zv.x : (c == 1) ? zv.y : (c == 2) ? zv.z : zv.w;
                float4 a = ld4(w1p + (d4 * 4 + c) * 32);
                float4 bq = ld4(w1p + (d4 * 4 + c) * 32 + 4);
                acc[0] += v * a.x;  acc[1] += v * a.y;  acc[2] += v * a.z;  acc[3] += v * a.w;
                acc[4] += v * bq.x; acc[5] += v * bq.y; acc[6] += v * bq.z; acc[7] += v * bq.w;
            }
        }
        const float* hp = hist + (size_t)(row0 + row) * 256 + tgt * 64;
        const float* w1q = w1p + 128 * 32;
        for (int d4 = 0; d4 < 16; ++d4) {
            float4 hv = ld4(hp + d4 * 4);
            #pragma unroll
            for (int c = 0; c < 4; ++c) {
                float v = (c == 0) ? hv.x : (c == 1) ? hv.y : (c == 2) ? hv.z : hv.w;
                float4 a = ld4(w1q + (d4 * 4 + c) * 32);
                float4 bq = ld4(w1q + (d4 * 4 + c) * 32 + 4);
                acc[0] += v * a.x;  acc[1] += v * a.y;  acc[2] += v * a.z;  acc[3] += v * a.w;
                acc[4] += v * bq.x; acc[5] += v * bq.y; acc[6] += v * bq.z; acc[7] += v * bq.w;
            }
        }
        float ps = 0.f;
        #pragma unroll
        for (int j = 0; j < 8; ++j) ps += fmaxf(acc[j], 0.f) * Wh2[tgt * 32 + j0 + j];
        ps += __shfl_xor(ps, 1);
        ps += __shfl_xor(ps, 2);
        if (gl == 0) out[(size_t)(row0 + row) * 4 + tgt] = fmaxf(ps + bh2[tgt], 0.f);
    }
}

extern "C" void kernel_launch(void* const* d_in, const int* in_sizes, int n_in,
                              void* d_out, int out_size, void* d_ws, size_t ws_size,
                              hipStream_t stream) {
    const float* x_static = (const float*)d_in[0];
    const float* x_kicks  = (const float*)d_in[1];
    const float* W_ke     = (const float*)d_in[2];
    const float* b_ke     = (const float*)d_in[3];
    const float* q_inner  = (const float*)d_in[4];
    const float* W_ge     = (const float*)d_in[5];
    const float* b_ge     = (const float*)d_in[6];
    const float* pos_emb  = (const float*)d_in[7];
    const float* q_outer  = (const float*)d_in[8];
    const float* log_temp = (const float*)d_in[9];
    const float* ln_g     = (const float*)d_in[10];
    const float* ln_b     = (const float*)d_in[11];
    const float* W1       = (const float*)d_in[12];
    const float* b1       = (const float*)d_in[13];
    const float* g1       = (const float*)d_in[14];
    const float* be1      = (const float*)d_in[15];
    const float* m1       = (const float*)d_in[16];
    const float* v1       = (const float*)d_in[17];
    const float* W2       = (const float*)d_in[18];
    const float* b2       = (const float*)d_in[19];
    const float* g2       = (const float*)d_in[20];
    const float* be2      = (const float*)d_in[21];
    const float* m2       = (const float*)d_in[22];
    const float* v2       = (const float*)d_in[23];
    const float* Wh1      = (const float*)d_in[24];
    const float* bh1      = (const float*)d_in[25];
    const float* Wh2      = (const float*)d_in[26];
    const float* bh2      = (const float*)d_in[27];
    const int* outer_mask = (const int*)d_in[28];
    const int* inner_mask = (const int*)d_in[29];

    float* hist = (float*)d_ws;           // 16384 * 256 floats = 16.8 MB
    float* out  = (float*)d_out;

    hist_kernel<<<16384, 64, 0, stream>>>(
        x_kicks, W_ke, b_ke, q_inner, W_ge, b_ge, pos_emb, q_outer,
        log_temp, ln_g, ln_b, outer_mask, inner_mask, hist);

    backbone_kernel<<<16384 / 16, 256, 0, stream>>>(
        x_static, W1, b1, g1, be1, m1, v1, W2, b2, g2, be2, m2, v2,
        Wh1, bh1, Wh2, bh2, hist, out);
}